// Round 5
// baseline (417.081 us; speedup 1.0000x reference)
//
#include <hip/hip_runtime.h>

#define NPT 16384
#define NEG_INF (-3.402823466e38f)

// ---- workspace byte offsets ----
#define OFF_PTS4  0u            // 16384 * 16          = 262144
#define OFF_WKC   262144u       // 128*128*4           = 65536
#define OFF_WAX   327680u       // 64*4*4              = 1024
#define OFF_WBX   328704u       // 1024
#define OFF_CBX   329728u       // 256
#define OFF_CBF   329984u       // 256
#define OFF_WUP   330240u       // 128*16*4            = 8192
#define OFF_BUP   338432u       // 512
#define OFF_TAU   338944u       // 16384*4             = 65536
#define OFF_CNT   404480u       // 16384*8*4           = 524288
#define OFF_KNN   928768u       // 16384*20*4          = 1310720
#define OFF_PART  2239488u      // 256*16*4            = 16384
#define OFF_CH    2255872u      // 256
#define OFF_R     2256128u      // reused region: push u16[16384][8][128] = 33554432
                                // after ksel: G(8MB), T2(8MB), F(8MB), F1(1MB), F2(1MB), SP(64KB)

__device__ __forceinline__ float pd_score(float qx2, float qy2, float qz2, float4 c) {
    // fast screening score = 2*dot(q,c) - |c|^2 (query-constant -|q|^2 dropped; same ranking)
    return fmaf(qx2, c.x, fmaf(qy2, c.y, fmaf(qz2, c.z, -c.w)));
}

__device__ __forceinline__ unsigned sortable_f(float v) {
    unsigned b = __float_as_uint(v);
    return (b & 0x80000000u) ? ~b : (b | 0x80000000u);
}

// ---------------- kernel 1: weight folds + pts4 ----------------
__global__ __launch_bounds__(256) void kprep(
    const float* __restrict__ xyz,
    const float* __restrict__ w1, const float* __restrict__ b1,
    const float* __restrict__ g1, const float* __restrict__ bb1,
    const float* __restrict__ m1, const float* __restrict__ v1,
    const float* __restrict__ w2, const float* __restrict__ b2,
    const float* __restrict__ g2, const float* __restrict__ bb2,
    const float* __restrict__ m2, const float* __restrict__ v2,
    const float* __restrict__ wup, const float* __restrict__ bup,
    const float* __restrict__ gu, const float* __restrict__ bu2,
    const float* __restrict__ mu, const float* __restrict__ vu,
    float* __restrict__ wsf)
{
    const int tid = threadIdx.x;
    if (blockIdx.x == 0) {
        float* WKC = wsf + OFF_WKC/4;
        float* WAX = wsf + OFF_WAX/4;
        float* WBX = wsf + OFF_WBX/4;
        float* CBX = wsf + OFF_CBX/4;
        float* CBF = wsf + OFF_CBF/4;
        float* WUP = wsf + OFF_WUP/4;
        float* BUP = wsf + OFF_BUP/4;
        for (int i = tid; i < 16384; i += 256) {
            int c = i >> 7, o = i & 127, oo = o & 63;
            float s2 = g2[oo] * rsqrtf(v2[oo] + 1e-5f);
            float val = (o < 64) ? s2 * w2[oo*256 + c]
                                 : s2 * (w2[oo*256 + 128 + c] - w2[oo*256 + c]);
            WKC[c*128 + o] = val;
        }
        if (tid < 64) {
            int o = tid;
            float s1 = g1[o] * rsqrtf(v1[o] + 1e-5f);
            WAX[o*4+0] = s1 * w1[o*6+0];
            WAX[o*4+1] = s1 * w1[o*6+1];
            WAX[o*4+2] = s1 * w1[o*6+2];
            WAX[o*4+3] = 0.f;
            WBX[o*4+0] = s1 * (w1[o*6+3] - w1[o*6+0]);
            WBX[o*4+1] = s1 * (w1[o*6+4] - w1[o*6+1]);
            WBX[o*4+2] = s1 * (w1[o*6+5] - w1[o*6+2]);
            WBX[o*4+3] = 0.f;
            CBX[o] = s1 * b1[o] + (bb1[o] - m1[o]*s1);
            float s2b = g2[o] * rsqrtf(v2[o] + 1e-5f);
            CBF[o] = s2b * b2[o] + (bb2[o] - m2[o]*s2b);
        }
        if (tid < 128) {
            int o = tid;
            float su = gu[o] * rsqrtf(vu[o] + 1e-5f);
            for (int c = 0; c < 16; ++c) WUP[o*16+c] = su * wup[o*16+c];
            BUP[o] = su * bup[o] + (bu2[o] - mu[o]*su);
        }
    } else {
        // np-f32-exact |p|^2: ((x*x + y*y) + z*z), no FMA contraction, matching
        // np.sum(xyz*xyz, axis=1) sequential f32 reduction.
        #pragma clang fp contract(off)
        int n = (blockIdx.x - 1)*256 + tid;
        float x = xyz[n], y = xyz[NPT+n], z = xyz[2*NPT+n];
        float4 p; p.x = x; p.y = y; p.z = z;
        p.w = (x*x + y*y) + z*z;
        ((float4*)(wsf + OFF_PTS4/4))[n] = p;
    }
}

// ---------------- kernel 2: per-query threshold tau ----------------
// tau[q] = (20th-largest of union(8 per-thread top-6) over candidates [0,1024)) - margin.
// union-20th <= subset-20th <= full-20th, and the 5e-4 margin covers all screening-score
// vs np-f32-pd discrepancies (<= ~3e-5) -> push survivors are a superset of np's top-20.
__global__ __launch_bounds__(256) void ktau(const float* __restrict__ wsf, float* __restrict__ tau)
{
    const float4* pts4 = (const float4*)(wsf + OFF_PTS4/4);
    __shared__ float4 sp[1024];
    __shared__ float t6[32][8][6];
    const int tid = threadIdx.x;
    for (int i = tid; i < 1024; i += 256) sp[i] = pts4[i];
    __syncthreads();
    const int ql = tid >> 3, t = tid & 7;
    const int q = blockIdx.x*32 + ql;
    float4 qp = pts4[q];
    float qx2 = qp.x + qp.x, qy2 = qp.y + qp.y, qz2 = qp.z + qp.z;
    float v0 = NEG_INF, v1 = NEG_INF, v2 = NEG_INF, v3 = NEG_INF, v4 = NEG_INF, v5 = NEG_INF;
    const int jb = t*128;
    for (int i = 0; i < 128; ++i) {
        float v = pd_score(qx2, qy2, qz2, sp[jb + i]);
        float n5 = v > v5 ? (v > v4 ? v4 : v) : v5;
        float n4 = v > v4 ? (v > v3 ? v3 : v) : v4;
        float n3 = v > v3 ? (v > v2 ? v2 : v) : v3;
        float n2 = v > v2 ? (v > v1 ? v1 : v) : v2;
        float n1 = v > v1 ? (v > v0 ? v0 : v) : v1;
        float n0 = v > v0 ? v : v0;
        v0 = n0; v1 = n1; v2 = n2; v3 = n3; v4 = n4; v5 = n5;
    }
    t6[ql][t][0] = v0; t6[ql][t][1] = v1; t6[ql][t][2] = v2;
    t6[ql][t][3] = v3; t6[ql][t][4] = v4; t6[ql][t][5] = v5;
    __syncthreads();
    if (t == 0) {
        int p0=0,p1=0,p2=0,p3=0,p4=0,p5=0,p6=0,p7=0;
        float last = NEG_INF;
        for (int it = 0; it < 20; ++it) {
            float best = NEG_INF; int bl = -1;
#define CHK(L, PL) { float h = t6[ql][L][(PL) < 6 ? (PL) : 5]; if (((PL) < 6) && (h > best)) { best = h; bl = L; } }
            CHK(0,p0) CHK(1,p1) CHK(2,p2) CHK(3,p3) CHK(4,p4) CHK(5,p5) CHK(6,p6) CHK(7,p7)
#undef CHK
            p0 += (bl==0); p1 += (bl==1); p2 += (bl==2); p3 += (bl==3);
            p4 += (bl==4); p5 += (bl==5); p6 += (bl==6); p7 += (bl==7);
            last = best;
        }
        tau[q] = last - 5e-4f;   // conservative margin (covers fmaf-chain vs np-f32 rounding)
    }
}

// ---------------- kernel 3: streaming push-scan ----------------
// grid: 64 query-groups x 8 candidate-chunks. Each thread owns 1 query, scans 2048 candidates.
__global__ __launch_bounds__(256) void kpush(const float* __restrict__ wsf,
                                             const float* __restrict__ tau,
                                             unsigned short* __restrict__ push,
                                             unsigned* __restrict__ cnt)
{
    const float4* pts4 = (const float4*)(wsf + OFF_PTS4/4);
    const int qg = blockIdx.x >> 3, c = blockIdx.x & 7;
    __shared__ float4 sp[2048];
    const int tid = threadIdx.x;
    const int jbase = c * 2048;
    for (int i = tid; i < 2048; i += 256) sp[i] = pts4[jbase + i];
    __syncthreads();
    const int q = qg*256 + tid;
    float4 a = pts4[q];
    float ax2 = a.x + a.x, ay2 = a.y + a.y, az2 = a.z + a.z;
    float t0 = tau[q];
    unsigned short* p0 = push + ((size_t)q*8 + c)*128;
    int c0 = 0;
    for (int jj = 0; jj < 2048; ++jj) {
        float s0 = pd_score(ax2, ay2, az2, sp[jj]);
        if (s0 >= t0 && c0 < 128) { p0[c0] = (unsigned short)(jbase + jj); ++c0; }
    }
    cnt[q*8 + c] = (unsigned)c0;
}

// ---------------- kernel 4: exact top-20 over survivors, np-f32 bit-exact ranking ----
// 8 threads per query (one per push chunk); per-thread top-20 kept in 20 NAMED u64
// registers (static uses only -> guaranteed VGPR allocation, no scratch); 8 sorted lists
// merged per query through LDS. Chunks are disjoint index ranges, so the u64 keys
// (sortable np-f32 score | inverted index) give the exact global order incl. tie-breaks.
// Downstream of idx everything is max-pooled over k, so only the SET of 20 matters.
#define KSHIFT(A,B) K##A = (kk > K##B) ? K##B : ((kk > K##A) ? kk : K##A);
__global__ __launch_bounds__(256) void ksel(const float* __restrict__ wsf,
                                            const unsigned short* __restrict__ push,
                                            const unsigned* __restrict__ cnt,
                                            unsigned* __restrict__ knn)
{
    #pragma clang fp contract(off)
    const float4* pts4 = (const float4*)(wsf + OFF_PTS4/4);
    __shared__ unsigned long long lk[32*163];   // per query: 8 lists * 20 keys (stride 163)
    const int tid = threadIdx.x;
    const int ql = tid >> 3, ch = tid & 7;
    const int q  = blockIdx.x*32 + ql;
    float4 qp = pts4[q];

    unsigned long long K00=0,K01=0,K02=0,K03=0,K04=0,K05=0,K06=0,K07=0,K08=0,K09=0,
                       K10=0,K11=0,K12=0,K13=0,K14=0,K15=0,K16=0,K17=0,K18=0,K19=0;

    int nc = (int)cnt[q*8 + ch]; if (nc > 128) nc = 128;
    const uint4* lp4 = (const uint4*)(push + ((size_t)q*8 + ch)*128);
    const int jbase = ch*2048;  (void)jbase;
    for (int i8 = 0; i8*8 < nc; ++i8) {
        uint4 pk = lp4[i8];
#pragma unroll
        for (int h = 0; h < 4; ++h) {
            unsigned w = (h==0) ? pk.x : (h==1) ? pk.y : (h==2) ? pk.z : pk.w;
#pragma unroll
            for (int s = 0; s < 2; ++s) {
                int ii = i8*8 + h*2 + s;
                if (ii < nc) {
                    int j = (int)((w >> (s*16)) & 0xFFFFu);
                    float4 cp = pts4[j];
                    float d  = (qp.x*cp.x + qp.y*cp.y) + qp.z*cp.z;
                    float pd = (2.0f*d - qp.w) - cp.w;
                    unsigned long long kk = ((unsigned long long)sortable_f(pd) << 14)
                                          | (unsigned long long)(16383 - j);
                    if (kk > K19) {
                        KSHIFT(19,18) KSHIFT(18,17) KSHIFT(17,16) KSHIFT(16,15)
                        KSHIFT(15,14) KSHIFT(14,13) KSHIFT(13,12) KSHIFT(12,11)
                        KSHIFT(11,10) KSHIFT(10,09) KSHIFT(09,08) KSHIFT(08,07)
                        KSHIFT(07,06) KSHIFT(06,05) KSHIFT(05,04) KSHIFT(04,03)
                        KSHIFT(03,02) KSHIFT(02,01) KSHIFT(01,00)
                        K00 = (kk > K00) ? kk : K00;
                    }
                }
            }
        }
    }
    {
        unsigned long long* dst = &lk[ql*163 + ch*20];
        dst[0]=K00;  dst[1]=K01;  dst[2]=K02;  dst[3]=K03;  dst[4]=K04;
        dst[5]=K05;  dst[6]=K06;  dst[7]=K07;  dst[8]=K08;  dst[9]=K09;
        dst[10]=K10; dst[11]=K11; dst[12]=K12; dst[13]=K13; dst[14]=K14;
        dst[15]=K15; dst[16]=K16; dst[17]=K17; dst[18]=K18; dst[19]=K19;
    }
    __syncthreads();
    if (tid < 32) {
        const int qq = blockIdx.x*32 + tid;
        const unsigned long long* base = &lk[tid*163];
        unsigned* kout = knn + (size_t)qq*20;
        int pp0=0,pp1=0,pp2=0,pp3=0,pp4=0,pp5=0,pp6=0,pp7=0;
        for (int it = 0; it < 20; ++it) {
            unsigned long long best = 0ull; int bc = -1;
#define MCHK(L) { unsigned long long h = (pp##L < 20) ? base[L*20 + pp##L] : 0ull; \
                  if (h > best) { best = h; bc = L; } }
            MCHK(0) MCHK(1) MCHK(2) MCHK(3) MCHK(4) MCHK(5) MCHK(6) MCHK(7)
#undef MCHK
            pp0 += (bc==0); pp1 += (bc==1); pp2 += (bc==2); pp3 += (bc==3);
            pp4 += (bc==4); pp5 += (bc==5); pp6 += (bc==6); pp7 += (bc==7);
            kout[it] = 16383u - (unsigned)(best & 0x3FFFull);
        }
    }
}

// ---------------- kernel 5: GEMM for feature part of G and T2 ----------------
// G[n][64+o] = F_n . WA_f[o]   ;  T2[n][64+o] = F_n . WB_f[o] + CB_f[o]
__global__ __launch_bounds__(128) void kgemm(const float* __restrict__ feat,
                                             const float* __restrict__ wsf,
                                             float* __restrict__ G, float* __restrict__ T2)
{
    __shared__ float As[32][64];
    __shared__ float Bs[32][128];
    const float* WKC = wsf + OFF_WKC/4;
    const float* CBF = wsf + OFF_CBF/4;
    const int tid = threadIdx.x;
    const int n0 = blockIdx.x * 64;
    const int tx = tid & 15, ty = tid >> 4;
    float acc[8][8] = {};
    for (int kc = 0; kc < 4; ++kc) {
        int c0 = kc * 32;
        for (int i = tid; i < 2048; i += 128) {
            int cl = i >> 6, nl = i & 63;
            As[cl][nl] = feat[(size_t)(c0 + cl)*NPT + n0 + nl];
        }
        for (int i = tid; i < 4096; i += 128) {
            int cl = i >> 7, ol = i & 127;
            Bs[cl][ol] = WKC[(c0 + cl)*128 + ol];
        }
        __syncthreads();
        for (int cc = 0; cc < 32; ++cc) {
            float av[8], bv[8];
#pragma unroll
            for (int r = 0; r < 8; ++r) av[r] = As[cc][ty*8 + r];
#pragma unroll
            for (int s = 0; s < 8; ++s) bv[s] = Bs[cc][tx*8 + s];
#pragma unroll
            for (int r = 0; r < 8; ++r)
#pragma unroll
                for (int s = 0; s < 8; ++s)
                    acc[r][s] = fmaf(av[r], bv[s], acc[r][s]);
        }
        __syncthreads();
    }
#pragma unroll
    for (int r = 0; r < 8; ++r) {
        int n = n0 + ty*8 + r;
        if (tx < 8) {
            float* dst = G + (size_t)n*128 + 64 + tx*8;
#pragma unroll
            for (int s = 0; s < 8; ++s) dst[s] = acc[r][s];
        } else {
            int ob = (tx - 8)*8;
            float* dst = T2 + (size_t)n*128 + 64 + ob;
#pragma unroll
            for (int s = 0; s < 8; ++s) dst[s] = acc[r][s] + CBF[ob + s];
        }
    }
}

// ---------------- kernel 6: xyz part of G and T2 ----------------
__global__ __launch_bounds__(256) void kxpart(const float* __restrict__ xyz,
                                              const float* __restrict__ wsf,
                                              float* __restrict__ G, float* __restrict__ T2)
{
    const float4* WAX = (const float4*)(wsf + OFF_WAX/4);
    const float4* WBX = (const float4*)(wsf + OFF_WBX/4);
    const float*  CBX = wsf + OFF_CBX/4;
    const int tid = threadIdx.x;
    const int o = tid & 63;
    const int n = blockIdx.x*4 + (tid >> 6);
    float x = xyz[n], y = xyz[NPT+n], z = xyz[2*NPT+n];
    float4 A = WAX[o], B = WBX[o];
    G[(size_t)n*128 + o]  = fmaf(x, A.x, fmaf(y, A.y, z*A.z));
    T2[(size_t)n*128 + o] = fmaf(x, B.x, fmaf(y, B.y, fmaf(z, B.z, CBX[o])));
}

// ---------------- kernel 7: gather + max-pool + f1/f2 + partials ----------------
__global__ __launch_bounds__(256) void kgather(const float* __restrict__ wsf,
                                               const unsigned* __restrict__ knn,
                                               const float* __restrict__ G,
                                               const float* __restrict__ T2,
                                               const float* __restrict__ wd1,
                                               const float* __restrict__ wd2,
                                               float* __restrict__ F, float* __restrict__ F1,
                                               float* __restrict__ F2, float* __restrict__ SPm,
                                               float* __restrict__ PART)
{
    __shared__ float fsh[64][136];
    __shared__ float w1s[16][136];
    __shared__ float w2s[16][136];
    __shared__ float f1sh[64][16];
    __shared__ float f2p[64][4];
    const int tid = threadIdx.x;
    for (int i = tid; i < 2048; i += 256) {
        int o = i >> 7, cc = i & 127;
        w1s[o][cc] = wd1[i];
        w2s[o][cc] = wd2[i];
    }
    const int nl = tid >> 2, qt = tid & 3;
    const int n = blockIdx.x*64 + nl;
    const unsigned* ip = knn + (size_t)n*20;
    float acc[32];
#pragma unroll
    for (int e = 0; e < 32; ++e) acc[e] = NEG_INF;
    for (int k = 0; k < 20; ++k) {
        unsigned j = ip[k];
        const float4* g4 = (const float4*)(G + (size_t)j*128 + qt*32);
#pragma unroll
        for (int r = 0; r < 8; ++r) {
            float4 gv = g4[r];
            acc[r*4+0] = fmaxf(acc[r*4+0], gv.x);
            acc[r*4+1] = fmaxf(acc[r*4+1], gv.y);
            acc[r*4+2] = fmaxf(acc[r*4+2], gv.z);
            acc[r*4+3] = fmaxf(acc[r*4+3], gv.w);
        }
    }
    const float4* t4 = (const float4*)(T2 + (size_t)n*128 + qt*32);
    float4* fg = (float4*)(F + (size_t)n*128 + qt*32);
    float4* fs = (float4*)&fsh[nl][qt*32];
#pragma unroll
    for (int r = 0; r < 8; ++r) {
        float4 tv = t4[r];
        float4 o4;
        o4.x = fmaxf(acc[r*4+0] + tv.x, 0.f);
        o4.y = fmaxf(acc[r*4+1] + tv.y, 0.f);
        o4.z = fmaxf(acc[r*4+2] + tv.z, 0.f);
        o4.w = fmaxf(acc[r*4+3] + tv.w, 0.f);
        fg[r] = o4; fs[r] = o4;
    }
    __syncthreads();
    // phase 2: f1/f2 (4 outputs each per thread)
    float a1[4] = {0,0,0,0}, a2[4] = {0,0,0,0};
    const int ob = qt*4;
    for (int c4 = 0; c4 < 32; ++c4) {
        float4 fv = ((const float4*)&fsh[nl][0])[c4];
#pragma unroll
        for (int r = 0; r < 4; ++r) {
            float4 wv1 = ((const float4*)&w1s[ob + r][0])[c4];
            float4 wv2 = ((const float4*)&w2s[ob + r][0])[c4];
            a1[r] = fmaf(fv.x, wv1.x, fmaf(fv.y, wv1.y, fmaf(fv.z, wv1.z, fmaf(fv.w, wv1.w, a1[r]))));
            a2[r] = fmaf(fv.x, wv2.x, fmaf(fv.y, wv2.y, fmaf(fv.z, wv2.z, fmaf(fv.w, wv2.w, a2[r]))));
        }
    }
    float s2sum = 0.f;
#pragma unroll
    for (int r = 0; r < 4; ++r) {
        a1[r] = fmaxf(a1[r], 0.f);
        a2[r] = fmaxf(a2[r], 0.f);
        s2sum += a2[r];
        F1[(size_t)n*16 + ob + r] = a1[r];
        F2[(size_t)n*16 + ob + r] = a2[r];
        f1sh[nl][ob + r] = a1[r];
    }
    f2p[nl][qt] = s2sum;
    __syncthreads();
    if (qt == 0)
        SPm[n] = (f2p[nl][0] + f2p[nl][1] + f2p[nl][2] + f2p[nl][3]) * (1.0f/16.0f);
    if (tid < 16) {
        float s = 0.f;
        for (int r = 0; r < 64; ++r) s += f1sh[r][tid];
        PART[blockIdx.x*16 + tid] = s;
    }
}

// ---------------- kernel 8: reduce channel mean ----------------
__global__ __launch_bounds__(64) void kch(const float* __restrict__ PART, float* __restrict__ CH)
{
    const int tid = threadIdx.x;
    if (tid < 16) {
        float s = 0.f;
        for (int b = 0; b < 256; ++b) s += PART[b*16 + tid];
        CH[tid] = s * (1.0f/16384.0f);
    }
}

// ---------------- kernel 9: final head + mish + transpose ----------------
__global__ __launch_bounds__(64) void kfinal(const float* __restrict__ wsf,
                                             const float* __restrict__ F,
                                             const float* __restrict__ F1,
                                             const float* __restrict__ F2,
                                             const float* __restrict__ SPm,
                                             const float* __restrict__ CH,
                                             float* __restrict__ out)
{
    const float* WUP = wsf + OFF_WUP/4;
    const float* BUP = wsf + OFF_BUP/4;
    const int n = blockIdx.x*64 + threadIdx.x;
    float spv = SPm[n];
    float fin[16];
    const float4* f14 = (const float4*)(F1 + (size_t)n*16);
    const float4* f24 = (const float4*)(F2 + (size_t)n*16);
#pragma unroll
    for (int c4 = 0; c4 < 4; ++c4) {
        float4 a = f14[c4], b = f24[c4];
        fin[c4*4+0] = sqrtf(fmaf(CH[c4*4+0], spv, 1e-12f)) + a.x + b.x;
        fin[c4*4+1] = sqrtf(fmaf(CH[c4*4+1], spv, 1e-12f)) + a.y + b.y;
        fin[c4*4+2] = sqrtf(fmaf(CH[c4*4+2], spv, 1e-12f)) + a.z + b.z;
        fin[c4*4+3] = sqrtf(fmaf(CH[c4*4+3], spv, 1e-12f)) + a.w + b.w;
    }
    const float4* fF = (const float4*)(F + (size_t)n*128);
    for (int o4 = 0; o4 < 32; ++o4) {
        float4 fv = fF[o4];
        float fa[4] = {fv.x, fv.y, fv.z, fv.w};
#pragma unroll
        for (int e = 0; e < 4; ++e) {
            int o = o4*4 + e;
            float u = BUP[o];
#pragma unroll
            for (int c = 0; c < 16; ++c) u = fmaf(fin[c], WUP[o*16 + c], u);
            u = fmaxf(u, 0.f);
            float fl = fa[e] - u;
            // mish: fl * tanh(softplus(fl)) ; tanh(log1p(e^x)) = ((1+e^x)^2-1)/((1+e^x)^2+1)
            float flc = fminf(fl, 15.f);
            float t = expf(flc);
            float w = 1.f + t;
            float w2 = w*w;
            float th = (w2 - 1.f) / (w2 + 1.f);
            float res = (fl > 15.f) ? fl : fl * th;
            out[(size_t)o*NPT + n] = res;
        }
    }
}

extern "C" void kernel_launch(void* const* d_in, const int* in_sizes, int n_in,
                              void* d_out, int out_size, void* d_ws, size_t ws_size,
                              hipStream_t stream) {
    const float* xyz  = (const float*)d_in[0];
    const float* feat = (const float*)d_in[1];
    const float* w1   = (const float*)d_in[2];
    const float* b1   = (const float*)d_in[3];
    const float* g1   = (const float*)d_in[4];
    const float* bb1  = (const float*)d_in[5];
    const float* m1   = (const float*)d_in[6];
    const float* v1   = (const float*)d_in[7];
    const float* w2   = (const float*)d_in[8];
    const float* b2   = (const float*)d_in[9];
    const float* g2   = (const float*)d_in[10];
    const float* bb2  = (const float*)d_in[11];
    const float* m2   = (const float*)d_in[12];
    const float* v2   = (const float*)d_in[13];
    const float* wd1  = (const float*)d_in[14];
    const float* wd2  = (const float*)d_in[15];
    const float* wup  = (const float*)d_in[16];
    const float* bup  = (const float*)d_in[17];
    const float* gu   = (const float*)d_in[18];
    const float* bu2  = (const float*)d_in[19];
    const float* mu   = (const float*)d_in[20];
    const float* vu   = (const float*)d_in[21];
    float* out = (float*)d_out;

    float* wsf = (float*)d_ws;
    unsigned short* push = (unsigned short*)((char*)d_ws + OFF_R);
    unsigned* cnt  = (unsigned*)((char*)d_ws + OFF_CNT);
    unsigned* knn  = (unsigned*)((char*)d_ws + OFF_KNN);
    float* TAU  = (float*)((char*)d_ws + OFF_TAU);
    float* PART = (float*)((char*)d_ws + OFF_PART);
    float* CH   = (float*)((char*)d_ws + OFF_CH);
    // region R reused after ksel
    float* G  = (float*)((char*)d_ws + OFF_R);
    float* T2 = G  + 2097152;
    float* F  = T2 + 2097152;
    float* F1 = F  + 2097152;
    float* F2 = F1 + 262144;
    float* SPm = F2 + 262144;

    kprep<<<dim3(65),  dim3(256), 0, stream>>>(xyz, w1,b1,g1,bb1,m1,v1,
                                               w2,b2,g2,bb2,m2,v2,
                                               wup,bup,gu,bu2,mu,vu, wsf);
    ktau <<<dim3(512), dim3(256), 0, stream>>>(wsf, TAU);
    kpush<<<dim3(512), dim3(256), 0, stream>>>(wsf, TAU, push, cnt);
    ksel <<<dim3(512), dim3(256), 0, stream>>>(wsf, push, cnt, knn);
    kgemm<<<dim3(256), dim3(128), 0, stream>>>(feat, wsf, G, T2);
    kxpart<<<dim3(4096), dim3(256), 0, stream>>>(xyz, wsf, G, T2);
    kgather<<<dim3(256), dim3(256), 0, stream>>>(wsf, knn, G, T2, wd1, wd2, F, F1, F2, SPm, PART);
    kch  <<<dim3(1),   dim3(64), 0, stream>>>(PART, CH);
    kfinal<<<dim3(256), dim3(64), 0, stream>>>(wsf, F, F1, F2, SPm, CH, out);
}

// Round 6
// 340.079 us; speedup vs baseline: 1.2264x; 1.2264x over previous
//
#include <hip/hip_runtime.h>

#define NPT 16384
#define NEG_INF (-3.402823466e38f)

// ---- workspace byte offsets ----
#define OFF_PTS4  0u            // 16384 * 16          = 262144
#define OFF_WKC   262144u       // 128*128*4           = 65536
#define OFF_WAX   327680u       // 64*4*4              = 1024
#define OFF_WBX   328704u       // 1024
#define OFF_CBX   329728u       // 256
#define OFF_CBF   329984u       // 256
#define OFF_WUP   330240u       // 128*16*4            = 8192
#define OFF_BUP   338432u       // 512
#define OFF_TAU   338944u       // 16384*4             = 65536
#define OFF_CNT   404480u       // u8[16384][16]       = 262144
#define OFF_KNN   666624u       // 16384*20*4          = 1310720
#define OFF_PART  1977344u      // 256*16*4            = 16384
#define OFF_CH    1993728u      // 256
#define OFF_R     1994240u      // reused: push u16[16384][16][64] = 33554432 (ends 35.55MB)
                                // after ksel: G(8MB), T2(8MB), F(8MB), F1(1MB), F2(1MB), SP(64KB)

__device__ __forceinline__ float pd_score(float qx2, float qy2, float qz2, float4 c) {
    // fast screening score = 2*dot(q,c) - |c|^2 (query-constant -|q|^2 dropped; same ranking)
    return fmaf(qx2, c.x, fmaf(qy2, c.y, fmaf(qz2, c.z, -c.w)));
}

__device__ __forceinline__ unsigned sortable_f(float v) {
    unsigned b = __float_as_uint(v);
    return (b & 0x80000000u) ? ~b : (b | 0x80000000u);
}

// ---------------- kernel 1: weight folds + pts4 ----------------
__global__ __launch_bounds__(256) void kprep(
    const float* __restrict__ xyz,
    const float* __restrict__ w1, const float* __restrict__ b1,
    const float* __restrict__ g1, const float* __restrict__ bb1,
    const float* __restrict__ m1, const float* __restrict__ v1,
    const float* __restrict__ w2, const float* __restrict__ b2,
    const float* __restrict__ g2, const float* __restrict__ bb2,
    const float* __restrict__ m2, const float* __restrict__ v2,
    const float* __restrict__ wup, const float* __restrict__ bup,
    const float* __restrict__ gu, const float* __restrict__ bu2,
    const float* __restrict__ mu, const float* __restrict__ vu,
    float* __restrict__ wsf)
{
    const int tid = threadIdx.x;
    if (blockIdx.x == 0) {
        float* WKC = wsf + OFF_WKC/4;
        float* WAX = wsf + OFF_WAX/4;
        float* WBX = wsf + OFF_WBX/4;
        float* CBX = wsf + OFF_CBX/4;
        float* CBF = wsf + OFF_CBF/4;
        float* WUP = wsf + OFF_WUP/4;
        float* BUP = wsf + OFF_BUP/4;
        for (int i = tid; i < 16384; i += 256) {
            int c = i >> 7, o = i & 127, oo = o & 63;
            float s2 = g2[oo] * rsqrtf(v2[oo] + 1e-5f);
            float val = (o < 64) ? s2 * w2[oo*256 + c]
                                 : s2 * (w2[oo*256 + 128 + c] - w2[oo*256 + c]);
            WKC[c*128 + o] = val;
        }
        if (tid < 64) {
            int o = tid;
            float s1 = g1[o] * rsqrtf(v1[o] + 1e-5f);
            WAX[o*4+0] = s1 * w1[o*6+0];
            WAX[o*4+1] = s1 * w1[o*6+1];
            WAX[o*4+2] = s1 * w1[o*6+2];
            WAX[o*4+3] = 0.f;
            WBX[o*4+0] = s1 * (w1[o*6+3] - w1[o*6+0]);
            WBX[o*4+1] = s1 * (w1[o*6+4] - w1[o*6+1]);
            WBX[o*4+2] = s1 * (w1[o*6+5] - w1[o*6+2]);
            WBX[o*4+3] = 0.f;
            CBX[o] = s1 * b1[o] + (bb1[o] - m1[o]*s1);
            float s2b = g2[o] * rsqrtf(v2[o] + 1e-5f);
            CBF[o] = s2b * b2[o] + (bb2[o] - m2[o]*s2b);
        }
        if (tid < 128) {
            int o = tid;
            float su = gu[o] * rsqrtf(vu[o] + 1e-5f);
            for (int c = 0; c < 16; ++c) WUP[o*16+c] = su * wup[o*16+c];
            BUP[o] = su * bup[o] + (bu2[o] - mu[o]*su);
        }
    } else {
        // np-f32-exact |p|^2: ((x*x + y*y) + z*z), no FMA contraction, matching
        // np.sum(xyz*xyz, axis=1) sequential f32 reduction.
        #pragma clang fp contract(off)
        int n = (blockIdx.x - 1)*256 + tid;
        float x = xyz[n], y = xyz[NPT+n], z = xyz[2*NPT+n];
        float4 p; p.x = x; p.y = y; p.z = z;
        p.w = (x*x + y*y) + z*z;
        ((float4*)(wsf + OFF_PTS4/4))[n] = p;
    }
}

// ---------------- kernel 2: per-query threshold tau ----------------
// tau[q] = (20th-largest of union(8 per-thread top-6) over candidates [0,1024)) - margin.
// union-20th <= subset-20th <= full-20th, and the 5e-4 margin covers all screening-score
// vs np-f32-pd discrepancies (<= ~3e-5) -> push survivors are a superset of np's top-20.
__global__ __launch_bounds__(256) void ktau(const float* __restrict__ wsf, float* __restrict__ tau)
{
    const float4* pts4 = (const float4*)(wsf + OFF_PTS4/4);
    __shared__ float4 sp[1024];
    __shared__ float t6[32][8][6];
    const int tid = threadIdx.x;
    for (int i = tid; i < 1024; i += 256) sp[i] = pts4[i];
    __syncthreads();
    const int ql = tid >> 3, t = tid & 7;
    const int q = blockIdx.x*32 + ql;
    float4 qp = pts4[q];
    float qx2 = qp.x + qp.x, qy2 = qp.y + qp.y, qz2 = qp.z + qp.z;
    float v0 = NEG_INF, v1 = NEG_INF, v2 = NEG_INF, v3 = NEG_INF, v4 = NEG_INF, v5 = NEG_INF;
    const int jb = t*128;
    for (int i = 0; i < 128; ++i) {
        float v = pd_score(qx2, qy2, qz2, sp[jb + i]);
        float n5 = v > v5 ? (v > v4 ? v4 : v) : v5;
        float n4 = v > v4 ? (v > v3 ? v3 : v) : v4;
        float n3 = v > v3 ? (v > v2 ? v2 : v) : v3;
        float n2 = v > v2 ? (v > v1 ? v1 : v) : v2;
        float n1 = v > v1 ? (v > v0 ? v0 : v) : v1;
        float n0 = v > v0 ? v : v0;
        v0 = n0; v1 = n1; v2 = n2; v3 = n3; v4 = n4; v5 = n5;
    }
    t6[ql][t][0] = v0; t6[ql][t][1] = v1; t6[ql][t][2] = v2;
    t6[ql][t][3] = v3; t6[ql][t][4] = v4; t6[ql][t][5] = v5;
    __syncthreads();
    if (t == 0) {
        int p0=0,p1=0,p2=0,p3=0,p4=0,p5=0,p6=0,p7=0;
        float last = NEG_INF;
        for (int it = 0; it < 20; ++it) {
            float best = NEG_INF; int bl = -1;
#define CHK(L, PL) { float h = t6[ql][L][(PL) < 6 ? (PL) : 5]; if (((PL) < 6) && (h > best)) { best = h; bl = L; } }
            CHK(0,p0) CHK(1,p1) CHK(2,p2) CHK(3,p3) CHK(4,p4) CHK(5,p5) CHK(6,p6) CHK(7,p7)
#undef CHK
            p0 += (bl==0); p1 += (bl==1); p2 += (bl==2); p3 += (bl==3);
            p4 += (bl==4); p5 += (bl==5); p6 += (bl==6); p7 += (bl==7);
            last = best;
        }
        tau[q] = last - 5e-4f;   // conservative margin (covers fmaf-chain vs np-f32 rounding)
    }
}

// ---------------- kernel 3: streaming push-scan ----------------
// grid: 64 query-groups x 16 candidate-chunks (1024 blocks, 4/CU, 16 waves/CU).
// Each thread owns 1 query, scans 1024 candidates, unrolled x4 for ILP.
__global__ __launch_bounds__(256) void kpush(const float* __restrict__ wsf,
                                             const float* __restrict__ tau,
                                             unsigned short* __restrict__ push,
                                             unsigned char* __restrict__ cnt)
{
    const float4* pts4 = (const float4*)(wsf + OFF_PTS4/4);
    const int qg = blockIdx.x >> 4, c = blockIdx.x & 15;
    __shared__ float4 sp[1024];
    const int tid = threadIdx.x;
    const int jbase = c * 1024;
    for (int i = tid; i < 1024; i += 256) sp[i] = pts4[jbase + i];
    __syncthreads();
    const int q = qg*256 + tid;
    float4 a = pts4[q];
    float ax2 = a.x + a.x, ay2 = a.y + a.y, az2 = a.z + a.z;
    float t0 = tau[q];
    unsigned short* p0 = push + ((size_t)q*16 + c)*64;
    int cw = 0;
    for (int jj = 0; jj < 1024; jj += 4) {
        float4 d0 = sp[jj], d1 = sp[jj+1], d2 = sp[jj+2], d3 = sp[jj+3];
        float s0 = pd_score(ax2, ay2, az2, d0);
        float s1 = pd_score(ax2, ay2, az2, d1);
        float s2 = pd_score(ax2, ay2, az2, d2);
        float s3 = pd_score(ax2, ay2, az2, d3);
        if (s0 >= t0 && cw < 64) { p0[cw] = (unsigned short)(jbase + jj);     ++cw; }
        if (s1 >= t0 && cw < 64) { p0[cw] = (unsigned short)(jbase + jj + 1); ++cw; }
        if (s2 >= t0 && cw < 64) { p0[cw] = (unsigned short)(jbase + jj + 2); ++cw; }
        if (s3 >= t0 && cw < 64) { p0[cw] = (unsigned short)(jbase + jj + 3); ++cw; }
    }
    cnt[q*16 + c] = (unsigned char)cw;
}

// ---------------- kernel 4: exact top-20 over survivors, np-f32 bit-exact ranking ----
// 8 threads per query, each draining TWO 64-entry push chunks into a register top-20
// (20 NAMED u64 regs -> no scratch); 8 sorted lists merged per query through LDS.
// Keys = (sortable np-f32 score | inverted index): exact global order incl. tie-breaks.
// Any global-top-20 key has <20 keys above it anywhere, so per-thread 20-deep lists
// cannot drop it. Downstream is max-pooled over k, so only the SET of 20 matters.
#define KSHIFT(A,B) K##A = (kk > K##B) ? K##B : ((kk > K##A) ? kk : K##A);
__global__ __launch_bounds__(256) void ksel(const float* __restrict__ wsf,
                                            const unsigned short* __restrict__ push,
                                            const unsigned char* __restrict__ cnt,
                                            unsigned* __restrict__ knn)
{
    #pragma clang fp contract(off)
    const float4* pts4 = (const float4*)(wsf + OFF_PTS4/4);
    __shared__ unsigned long long lk[32*163];   // per query: 8 lists * 20 keys (stride 163)
    const int tid = threadIdx.x;
    const int ql = tid >> 3, ch = tid & 7;
    const int q  = blockIdx.x*32 + ql;
    float4 qp = pts4[q];

    unsigned long long K00=0,K01=0,K02=0,K03=0,K04=0,K05=0,K06=0,K07=0,K08=0,K09=0,
                       K10=0,K11=0,K12=0,K13=0,K14=0,K15=0,K16=0,K17=0,K18=0,K19=0;

#pragma unroll
    for (int half = 0; half < 2; ++half) {
        const int cc = ch*2 + half;
        int nc = (int)cnt[q*16 + cc]; if (nc > 64) nc = 64;
        const uint4* lp4 = (const uint4*)(push + ((size_t)q*16 + cc)*64);
        for (int i8 = 0; i8*8 < nc; ++i8) {
            uint4 pk = lp4[i8];
#pragma unroll
            for (int h = 0; h < 4; ++h) {
                unsigned w = (h==0) ? pk.x : (h==1) ? pk.y : (h==2) ? pk.z : pk.w;
#pragma unroll
                for (int s = 0; s < 2; ++s) {
                    int ii = i8*8 + h*2 + s;
                    if (ii < nc) {
                        int j = (int)((w >> (s*16)) & 0xFFFFu);
                        float4 cp = pts4[j];
                        float d  = (qp.x*cp.x + qp.y*cp.y) + qp.z*cp.z;
                        float pd = (2.0f*d - qp.w) - cp.w;
                        unsigned long long kk = ((unsigned long long)sortable_f(pd) << 14)
                                              | (unsigned long long)(16383 - j);
                        if (kk > K19) {
                            KSHIFT(19,18) KSHIFT(18,17) KSHIFT(17,16) KSHIFT(16,15)
                            KSHIFT(15,14) KSHIFT(14,13) KSHIFT(13,12) KSHIFT(12,11)
                            KSHIFT(11,10) KSHIFT(10,09) KSHIFT(09,08) KSHIFT(08,07)
                            KSHIFT(07,06) KSHIFT(06,05) KSHIFT(05,04) KSHIFT(04,03)
                            KSHIFT(03,02) KSHIFT(02,01) KSHIFT(01,00)
                            K00 = (kk > K00) ? kk : K00;
                        }
                    }
                }
            }
        }
    }
    {
        unsigned long long* dst = &lk[ql*163 + ch*20];
        dst[0]=K00;  dst[1]=K01;  dst[2]=K02;  dst[3]=K03;  dst[4]=K04;
        dst[5]=K05;  dst[6]=K06;  dst[7]=K07;  dst[8]=K08;  dst[9]=K09;
        dst[10]=K10; dst[11]=K11; dst[12]=K12; dst[13]=K13; dst[14]=K14;
        dst[15]=K15; dst[16]=K16; dst[17]=K17; dst[18]=K18; dst[19]=K19;
    }
    __syncthreads();
    if (tid < 32) {
        const int qq = blockIdx.x*32 + tid;
        const unsigned long long* base = &lk[tid*163];
        unsigned* kout = knn + (size_t)qq*20;
        int pp0=0,pp1=0,pp2=0,pp3=0,pp4=0,pp5=0,pp6=0,pp7=0;
        for (int it = 0; it < 20; ++it) {
            unsigned long long best = 0ull; int bc = -1;
#define MCHK(L) { unsigned long long h = (pp##L < 20) ? base[L*20 + pp##L] : 0ull; \
                  if (h > best) { best = h; bc = L; } }
            MCHK(0) MCHK(1) MCHK(2) MCHK(3) MCHK(4) MCHK(5) MCHK(6) MCHK(7)
#undef MCHK
            pp0 += (bc==0); pp1 += (bc==1); pp2 += (bc==2); pp3 += (bc==3);
            pp4 += (bc==4); pp5 += (bc==5); pp6 += (bc==6); pp7 += (bc==7);
            kout[it] = 16383u - (unsigned)(best & 0x3FFFull);
        }
    }
}

// ---------------- kernel 5: GEMM for feature part of G and T2 ----------------
// G[n][64+o] = F_n . WA_f[o]   ;  T2[n][64+o] = F_n . WB_f[o] + CB_f[o]
__global__ __launch_bounds__(128) void kgemm(const float* __restrict__ feat,
                                             const float* __restrict__ wsf,
                                             float* __restrict__ G, float* __restrict__ T2)
{
    __shared__ float As[32][64];
    __shared__ float Bs[32][128];
    const float* WKC = wsf + OFF_WKC/4;
    const float* CBF = wsf + OFF_CBF/4;
    const int tid = threadIdx.x;
    const int n0 = blockIdx.x * 64;
    const int tx = tid & 15, ty = tid >> 4;
    float acc[8][8] = {};
    for (int kc = 0; kc < 4; ++kc) {
        int c0 = kc * 32;
        for (int i = tid; i < 2048; i += 128) {
            int cl = i >> 6, nl = i & 63;
            As[cl][nl] = feat[(size_t)(c0 + cl)*NPT + n0 + nl];
        }
        for (int i = tid; i < 4096; i += 128) {
            int cl = i >> 7, ol = i & 127;
            Bs[cl][ol] = WKC[(c0 + cl)*128 + ol];
        }
        __syncthreads();
        for (int cc = 0; cc < 32; ++cc) {
            float av[8], bv[8];
#pragma unroll
            for (int r = 0; r < 8; ++r) av[r] = As[cc][ty*8 + r];
#pragma unroll
            for (int s = 0; s < 8; ++s) bv[s] = Bs[cc][tx*8 + s];
#pragma unroll
            for (int r = 0; r < 8; ++r)
#pragma unroll
                for (int s = 0; s < 8; ++s)
                    acc[r][s] = fmaf(av[r], bv[s], acc[r][s]);
        }
        __syncthreads();
    }
#pragma unroll
    for (int r = 0; r < 8; ++r) {
        int n = n0 + ty*8 + r;
        if (tx < 8) {
            float* dst = G + (size_t)n*128 + 64 + tx*8;
#pragma unroll
            for (int s = 0; s < 8; ++s) dst[s] = acc[r][s];
        } else {
            int ob = (tx - 8)*8;
            float* dst = T2 + (size_t)n*128 + 64 + ob;
#pragma unroll
            for (int s = 0; s < 8; ++s) dst[s] = acc[r][s] + CBF[ob + s];
        }
    }
}

// ---------------- kernel 6: xyz part of G and T2 ----------------
__global__ __launch_bounds__(256) void kxpart(const float* __restrict__ xyz,
                                              const float* __restrict__ wsf,
                                              float* __restrict__ G, float* __restrict__ T2)
{
    const float4* WAX = (const float4*)(wsf + OFF_WAX/4);
    const float4* WBX = (const float4*)(wsf + OFF_WBX/4);
    const float*  CBX = wsf + OFF_CBX/4;
    const int tid = threadIdx.x;
    const int o = tid & 63;
    const int n = blockIdx.x*4 + (tid >> 6);
    float x = xyz[n], y = xyz[NPT+n], z = xyz[2*NPT+n];
    float4 A = WAX[o], B = WBX[o];
    G[(size_t)n*128 + o]  = fmaf(x, A.x, fmaf(y, A.y, z*A.z));
    T2[(size_t)n*128 + o] = fmaf(x, B.x, fmaf(y, B.y, fmaf(z, B.z, CBX[o])));
}

// ---------------- kernel 7: gather + max-pool + f1/f2 + partials ----------------
__global__ __launch_bounds__(256) void kgather(const float* __restrict__ wsf,
                                               const unsigned* __restrict__ knn,
                                               const float* __restrict__ G,
                                               const float* __restrict__ T2,
                                               const float* __restrict__ wd1,
                                               const float* __restrict__ wd2,
                                               float* __restrict__ F, float* __restrict__ F1,
                                               float* __restrict__ F2, float* __restrict__ SPm,
                                               float* __restrict__ PART)
{
    __shared__ float fsh[64][136];
    __shared__ float w1s[16][136];
    __shared__ float w2s[16][136];
    __shared__ float f1sh[64][16];
    __shared__ float f2p[64][4];
    const int tid = threadIdx.x;
    for (int i = tid; i < 2048; i += 256) {
        int o = i >> 7, cc = i & 127;
        w1s[o][cc] = wd1[i];
        w2s[o][cc] = wd2[i];
    }
    const int nl = tid >> 2, qt = tid & 3;
    const int n = blockIdx.x*64 + nl;
    const unsigned* ip = knn + (size_t)n*20;
    float acc[32];
#pragma unroll
    for (int e = 0; e < 32; ++e) acc[e] = NEG_INF;
    for (int k = 0; k < 20; ++k) {
        unsigned j = ip[k];
        const float4* g4 = (const float4*)(G + (size_t)j*128 + qt*32);
#pragma unroll
        for (int r = 0; r < 8; ++r) {
            float4 gv = g4[r];
            acc[r*4+0] = fmaxf(acc[r*4+0], gv.x);
            acc[r*4+1] = fmaxf(acc[r*4+1], gv.y);
            acc[r*4+2] = fmaxf(acc[r*4+2], gv.z);
            acc[r*4+3] = fmaxf(acc[r*4+3], gv.w);
        }
    }
    const float4* t4 = (const float4*)(T2 + (size_t)n*128 + qt*32);
    float4* fg = (float4*)(F + (size_t)n*128 + qt*32);
    float4* fs = (float4*)&fsh[nl][qt*32];
#pragma unroll
    for (int r = 0; r < 8; ++r) {
        float4 tv = t4[r];
        float4 o4;
        o4.x = fmaxf(acc[r*4+0] + tv.x, 0.f);
        o4.y = fmaxf(acc[r*4+1] + tv.y, 0.f);
        o4.z = fmaxf(acc[r*4+2] + tv.z, 0.f);
        o4.w = fmaxf(acc[r*4+3] + tv.w, 0.f);
        fg[r] = o4; fs[r] = o4;
    }
    __syncthreads();
    // phase 2: f1/f2 (4 outputs each per thread)
    float a1[4] = {0,0,0,0}, a2[4] = {0,0,0,0};
    const int ob = qt*4;
    for (int c4 = 0; c4 < 32; ++c4) {
        float4 fv = ((const float4*)&fsh[nl][0])[c4];
#pragma unroll
        for (int r = 0; r < 4; ++r) {
            float4 wv1 = ((const float4*)&w1s[ob + r][0])[c4];
            float4 wv2 = ((const float4*)&w2s[ob + r][0])[c4];
            a1[r] = fmaf(fv.x, wv1.x, fmaf(fv.y, wv1.y, fmaf(fv.z, wv1.z, fmaf(fv.w, wv1.w, a1[r]))));
            a2[r] = fmaf(fv.x, wv2.x, fmaf(fv.y, wv2.y, fmaf(fv.z, wv2.z, fmaf(fv.w, wv2.w, a2[r]))));
        }
    }
    float s2sum = 0.f;
#pragma unroll
    for (int r = 0; r < 4; ++r) {
        a1[r] = fmaxf(a1[r], 0.f);
        a2[r] = fmaxf(a2[r], 0.f);
        s2sum += a2[r];
        F1[(size_t)n*16 + ob + r] = a1[r];
        F2[(size_t)n*16 + ob + r] = a2[r];
        f1sh[nl][ob + r] = a1[r];
    }
    f2p[nl][qt] = s2sum;
    __syncthreads();
    if (qt == 0)
        SPm[n] = (f2p[nl][0] + f2p[nl][1] + f2p[nl][2] + f2p[nl][3]) * (1.0f/16.0f);
    if (tid < 16) {
        float s = 0.f;
        for (int r = 0; r < 64; ++r) s += f1sh[r][tid];
        PART[blockIdx.x*16 + tid] = s;
    }
}

// ---------------- kernel 8: reduce channel mean ----------------
__global__ __launch_bounds__(64) void kch(const float* __restrict__ PART, float* __restrict__ CH)
{
    const int tid = threadIdx.x;
    if (tid < 16) {
        float s = 0.f;
        for (int b = 0; b < 256; ++b) s += PART[b*16 + tid];
        CH[tid] = s * (1.0f/16384.0f);
    }
}

// ---------------- kernel 9: final head + mish + transpose ----------------
__global__ __launch_bounds__(64) void kfinal(const float* __restrict__ wsf,
                                             const float* __restrict__ F,
                                             const float* __restrict__ F1,
                                             const float* __restrict__ F2,
                                             const float* __restrict__ SPm,
                                             const float* __restrict__ CH,
                                             float* __restrict__ out)
{
    const float* WUP = wsf + OFF_WUP/4;
    const float* BUP = wsf + OFF_BUP/4;
    const int n = blockIdx.x*64 + threadIdx.x;
    float spv = SPm[n];
    float fin[16];
    const float4* f14 = (const float4*)(F1 + (size_t)n*16);
    const float4* f24 = (const float4*)(F2 + (size_t)n*16);
#pragma unroll
    for (int c4 = 0; c4 < 4; ++c4) {
        float4 a = f14[c4], b = f24[c4];
        fin[c4*4+0] = sqrtf(fmaf(CH[c4*4+0], spv, 1e-12f)) + a.x + b.x;
        fin[c4*4+1] = sqrtf(fmaf(CH[c4*4+1], spv, 1e-12f)) + a.y + b.y;
        fin[c4*4+2] = sqrtf(fmaf(CH[c4*4+2], spv, 1e-12f)) + a.z + b.z;
        fin[c4*4+3] = sqrtf(fmaf(CH[c4*4+3], spv, 1e-12f)) + a.w + b.w;
    }
    const float4* fF = (const float4*)(F + (size_t)n*128);
    for (int o4 = 0; o4 < 32; ++o4) {
        float4 fv = fF[o4];
        float fa[4] = {fv.x, fv.y, fv.z, fv.w};
#pragma unroll
        for (int e = 0; e < 4; ++e) {
            int o = o4*4 + e;
            float u = BUP[o];
#pragma unroll
            for (int c = 0; c < 16; ++c) u = fmaf(fin[c], WUP[o*16 + c], u);
            u = fmaxf(u, 0.f);
            float fl = fa[e] - u;
            // mish: fl * tanh(softplus(fl)) ; tanh(log1p(e^x)) = ((1+e^x)^2-1)/((1+e^x)^2+1)
            float flc = fminf(fl, 15.f);
            float t = expf(flc);
            float w = 1.f + t;
            float w2 = w*w;
            float th = (w2 - 1.f) / (w2 + 1.f);
            float res = (fl > 15.f) ? fl : fl * th;
            out[(size_t)o*NPT + n] = res;
        }
    }
}

extern "C" void kernel_launch(void* const* d_in, const int* in_sizes, int n_in,
                              void* d_out, int out_size, void* d_ws, size_t ws_size,
                              hipStream_t stream) {
    const float* xyz  = (const float*)d_in[0];
    const float* feat = (const float*)d_in[1];
    const float* w1   = (const float*)d_in[2];
    const float* b1   = (const float*)d_in[3];
    const float* g1   = (const float*)d_in[4];
    const float* bb1  = (const float*)d_in[5];
    const float* m1   = (const float*)d_in[6];
    const float* v1   = (const float*)d_in[7];
    const float* w2   = (const float*)d_in[8];
    const float* b2   = (const float*)d_in[9];
    const float* g2   = (const float*)d_in[10];
    const float* bb2  = (const float*)d_in[11];
    const float* m2   = (const float*)d_in[12];
    const float* v2   = (const float*)d_in[13];
    const float* wd1  = (const float*)d_in[14];
    const float* wd2  = (const float*)d_in[15];
    const float* wup  = (const float*)d_in[16];
    const float* bup  = (const float*)d_in[17];
    const float* gu   = (const float*)d_in[18];
    const float* bu2  = (const float*)d_in[19];
    const float* mu   = (const float*)d_in[20];
    const float* vu   = (const float*)d_in[21];
    float* out = (float*)d_out;

    float* wsf = (float*)d_ws;
    unsigned short* push = (unsigned short*)((char*)d_ws + OFF_R);
    unsigned char* cnt  = (unsigned char*)((char*)d_ws + OFF_CNT);
    unsigned* knn  = (unsigned*)((char*)d_ws + OFF_KNN);
    float* TAU  = (float*)((char*)d_ws + OFF_TAU);
    float* PART = (float*)((char*)d_ws + OFF_PART);
    float* CH   = (float*)((char*)d_ws + OFF_CH);
    // region R reused after ksel
    float* G  = (float*)((char*)d_ws + OFF_R);
    float* T2 = G  + 2097152;
    float* F  = T2 + 2097152;
    float* F1 = F  + 2097152;
    float* F2 = F1 + 262144;
    float* SPm = F2 + 262144;

    kprep<<<dim3(65),  dim3(256), 0, stream>>>(xyz, w1,b1,g1,bb1,m1,v1,
                                               w2,b2,g2,bb2,m2,v2,
                                               wup,bup,gu,bu2,mu,vu, wsf);
    ktau <<<dim3(512), dim3(256), 0, stream>>>(wsf, TAU);
    kpush<<<dim3(1024), dim3(256), 0, stream>>>(wsf, TAU, push, cnt);
    ksel <<<dim3(512), dim3(256), 0, stream>>>(wsf, push, cnt, knn);
    kgemm<<<dim3(256), dim3(128), 0, stream>>>(feat, wsf, G, T2);
    kxpart<<<dim3(4096), dim3(256), 0, stream>>>(xyz, wsf, G, T2);
    kgather<<<dim3(256), dim3(256), 0, stream>>>(wsf, knn, G, T2, wd1, wd2, F, F1, F2, SPm, PART);
    kch  <<<dim3(1),   dim3(64), 0, stream>>>(PART, CH);
    kfinal<<<dim3(256), dim3(64), 0, stream>>>(wsf, F, F1, F2, SPm, CH, out);
}

// Round 7
// 292.511 us; speedup vs baseline: 1.4259x; 1.1626x over previous
//
#include <hip/hip_runtime.h>

#define NPT 16384
#define NEG_INF (-3.402823466e38f)

// ---- workspace byte offsets ----
#define OFF_PTS4  0u            // 16384 * 16          = 262144
#define OFF_WKC   262144u       // 128*128*4           = 65536
#define OFF_WAX   327680u       // 64*4*4              = 1024
#define OFF_WBX   328704u       // 1024
#define OFF_CBX   329728u       // 256
#define OFF_CBF   329984u       // 256
#define OFF_WUP   330240u       // 128*16*4            = 8192
#define OFF_BUP   338432u       // 512
#define OFF_TAU   338944u       // 16384*4             = 65536
#define OFF_CNT   404480u       // u8[16384][16]       = 262144
#define OFF_KNN   666624u       // 16384*20*4          = 1310720
#define OFF_PART  1977344u      // 256*16*4            = 16384
#define OFF_CH    1993728u      // 256
#define OFF_R     1994240u      // reused: push u16[16384][16][64] = 33554432 (ends 35.55MB)
                                // after ksel: G(8MB), T2(8MB), F(8MB), F1(1MB), F2(1MB), SP(64KB)

__device__ __forceinline__ float pd_score(float qx2, float qy2, float qz2, float4 c) {
    // fast screening score = 2*dot(q,c) - |c|^2 (query-constant -|q|^2 dropped; same ranking)
    return fmaf(qx2, c.x, fmaf(qy2, c.y, fmaf(qz2, c.z, -c.w)));
}

__device__ __forceinline__ unsigned sortable_f(float v) {
    unsigned b = __float_as_uint(v);
    return (b & 0x80000000u) ? ~b : (b | 0x80000000u);
}

// ---------------- kernel 1: weight folds + pts4 ----------------
__global__ __launch_bounds__(256) void kprep(
    const float* __restrict__ xyz,
    const float* __restrict__ w1, const float* __restrict__ b1,
    const float* __restrict__ g1, const float* __restrict__ bb1,
    const float* __restrict__ m1, const float* __restrict__ v1,
    const float* __restrict__ w2, const float* __restrict__ b2,
    const float* __restrict__ g2, const float* __restrict__ bb2,
    const float* __restrict__ m2, const float* __restrict__ v2,
    const float* __restrict__ wup, const float* __restrict__ bup,
    const float* __restrict__ gu, const float* __restrict__ bu2,
    const float* __restrict__ mu, const float* __restrict__ vu,
    float* __restrict__ wsf)
{
    const int tid = threadIdx.x;
    if (blockIdx.x == 0) {
        float* WKC = wsf + OFF_WKC/4;
        float* WAX = wsf + OFF_WAX/4;
        float* WBX = wsf + OFF_WBX/4;
        float* CBX = wsf + OFF_CBX/4;
        float* CBF = wsf + OFF_CBF/4;
        float* WUP = wsf + OFF_WUP/4;
        float* BUP = wsf + OFF_BUP/4;
        for (int i = tid; i < 16384; i += 256) {
            int c = i >> 7, o = i & 127, oo = o & 63;
            float s2 = g2[oo] * rsqrtf(v2[oo] + 1e-5f);
            float val = (o < 64) ? s2 * w2[oo*256 + c]
                                 : s2 * (w2[oo*256 + 128 + c] - w2[oo*256 + c]);
            WKC[c*128 + o] = val;
        }
        if (tid < 64) {
            int o = tid;
            float s1 = g1[o] * rsqrtf(v1[o] + 1e-5f);
            WAX[o*4+0] = s1 * w1[o*6+0];
            WAX[o*4+1] = s1 * w1[o*6+1];
            WAX[o*4+2] = s1 * w1[o*6+2];
            WAX[o*4+3] = 0.f;
            WBX[o*4+0] = s1 * (w1[o*6+3] - w1[o*6+0]);
            WBX[o*4+1] = s1 * (w1[o*6+4] - w1[o*6+1]);
            WBX[o*4+2] = s1 * (w1[o*6+5] - w1[o*6+2]);
            WBX[o*4+3] = 0.f;
            CBX[o] = s1 * b1[o] + (bb1[o] - m1[o]*s1);
            float s2b = g2[o] * rsqrtf(v2[o] + 1e-5f);
            CBF[o] = s2b * b2[o] + (bb2[o] - m2[o]*s2b);
        }
        if (tid < 128) {
            int o = tid;
            float su = gu[o] * rsqrtf(vu[o] + 1e-5f);
            for (int c = 0; c < 16; ++c) WUP[o*16+c] = su * wup[o*16+c];
            BUP[o] = su * bup[o] + (bu2[o] - mu[o]*su);
        }
    } else {
        // np-f32-exact |p|^2: ((x*x + y*y) + z*z), no FMA contraction, matching
        // np.sum(xyz*xyz, axis=1) sequential f32 reduction.
        #pragma clang fp contract(off)
        int n = (blockIdx.x - 1)*256 + tid;
        float x = xyz[n], y = xyz[NPT+n], z = xyz[2*NPT+n];
        float4 p; p.x = x; p.y = y; p.z = z;
        p.w = (x*x + y*y) + z*z;
        ((float4*)(wsf + OFF_PTS4/4))[n] = p;
    }
}

// ---------------- kernel 2: per-query threshold tau ----------------
// tau[q] = (20th-largest of union(8 per-thread top-6) over candidates [0,1024)) - margin.
// union-20th <= subset-20th <= full-20th, and the 5e-4 margin covers all screening-score
// vs np-f32-pd discrepancies (<= ~3e-5) -> push survivors are a superset of np's top-20.
__global__ __launch_bounds__(256) void ktau(const float* __restrict__ wsf, float* __restrict__ tau)
{
    const float4* pts4 = (const float4*)(wsf + OFF_PTS4/4);
    __shared__ float4 sp[1024];
    __shared__ float t6[32][8][6];
    const int tid = threadIdx.x;
    for (int i = tid; i < 1024; i += 256) sp[i] = pts4[i];
    __syncthreads();
    const int ql = tid >> 3, t = tid & 7;
    const int q = blockIdx.x*32 + ql;
    float4 qp = pts4[q];
    float qx2 = qp.x + qp.x, qy2 = qp.y + qp.y, qz2 = qp.z + qp.z;
    float v0 = NEG_INF, v1 = NEG_INF, v2 = NEG_INF, v3 = NEG_INF, v4 = NEG_INF, v5 = NEG_INF;
    const int jb = t*128;
    for (int i = 0; i < 128; ++i) {
        float v = pd_score(qx2, qy2, qz2, sp[jb + i]);
        float n5 = v > v5 ? (v > v4 ? v4 : v) : v5;
        float n4 = v > v4 ? (v > v3 ? v3 : v) : v4;
        float n3 = v > v3 ? (v > v2 ? v2 : v) : v3;
        float n2 = v > v2 ? (v > v1 ? v1 : v) : v2;
        float n1 = v > v1 ? (v > v0 ? v0 : v) : v1;
        float n0 = v > v0 ? v : v0;
        v0 = n0; v1 = n1; v2 = n2; v3 = n3; v4 = n4; v5 = n5;
    }
    t6[ql][t][0] = v0; t6[ql][t][1] = v1; t6[ql][t][2] = v2;
    t6[ql][t][3] = v3; t6[ql][t][4] = v4; t6[ql][t][5] = v5;
    __syncthreads();
    if (t == 0) {
        int p0=0,p1=0,p2=0,p3=0,p4=0,p5=0,p6=0,p7=0;
        float last = NEG_INF;
        for (int it = 0; it < 20; ++it) {
            float best = NEG_INF; int bl = -1;
#define CHK(L, PL) { float h = t6[ql][L][(PL) < 6 ? (PL) : 5]; if (((PL) < 6) && (h > best)) { best = h; bl = L; } }
            CHK(0,p0) CHK(1,p1) CHK(2,p2) CHK(3,p3) CHK(4,p4) CHK(5,p5) CHK(6,p6) CHK(7,p7)
#undef CHK
            p0 += (bl==0); p1 += (bl==1); p2 += (bl==2); p3 += (bl==3);
            p4 += (bl==4); p5 += (bl==5); p6 += (bl==6); p7 += (bl==7);
            last = best;
        }
        tau[q] = last - 5e-4f;   // conservative margin (covers fmaf-chain vs np-f32 rounding)
    }
}

// ---------------- kernel 3: streaming push-scan ----------------
// grid: 64 query-groups x 16 candidate-chunks (1024 blocks, 4/CU, 16 waves/CU).
// Each thread owns 1 query, scans 1024 candidates, unrolled x4 for ILP.
__global__ __launch_bounds__(256) void kpush(const float* __restrict__ wsf,
                                             const float* __restrict__ tau,
                                             unsigned short* __restrict__ push,
                                             unsigned char* __restrict__ cnt)
{
    const float4* pts4 = (const float4*)(wsf + OFF_PTS4/4);
    const int qg = blockIdx.x >> 4, c = blockIdx.x & 15;
    __shared__ float4 sp[1024];
    const int tid = threadIdx.x;
    const int jbase = c * 1024;
    for (int i = tid; i < 1024; i += 256) sp[i] = pts4[jbase + i];
    __syncthreads();
    const int q = qg*256 + tid;
    float4 a = pts4[q];
    float ax2 = a.x + a.x, ay2 = a.y + a.y, az2 = a.z + a.z;
    float t0 = tau[q];
    unsigned short* p0 = push + ((size_t)q*16 + c)*64;
    int cw = 0;
    for (int jj = 0; jj < 1024; jj += 4) {
        float4 d0 = sp[jj], d1 = sp[jj+1], d2 = sp[jj+2], d3 = sp[jj+3];
        float s0 = pd_score(ax2, ay2, az2, d0);
        float s1 = pd_score(ax2, ay2, az2, d1);
        float s2 = pd_score(ax2, ay2, az2, d2);
        float s3 = pd_score(ax2, ay2, az2, d3);
        if (s0 >= t0 && cw < 64) { p0[cw] = (unsigned short)(jbase + jj);     ++cw; }
        if (s1 >= t0 && cw < 64) { p0[cw] = (unsigned short)(jbase + jj + 1); ++cw; }
        if (s2 >= t0 && cw < 64) { p0[cw] = (unsigned short)(jbase + jj + 2); ++cw; }
        if (s3 >= t0 && cw < 64) { p0[cw] = (unsigned short)(jbase + jj + 3); ++cw; }
    }
    cnt[q*16 + c] = (unsigned char)cw;
}

// ---------------- kernel 4: exact top-20, wave-per-query register extraction ----------
// One 64-lane wave per query. Lane L owns chunk L>>2, entries (L&3)+4k of that push
// list (~5 survivors/lane), scored np-f32 bit-exact:
//   d = ((x*x' + y*y') + z*z');  pd = ((2f*d - xx_q) - xx_c)   [fp contract off]
// and inserted into a 12-deep NAMED-register descending list (no scratch, no LDS).
// Then 20 rounds of {wave-wide u64 max via shfl_xor; owning lane pops}. Keys embed the
// inverted index -> unique -> exact np top_k order incl. lowest-index tie-breaks.
// Coverage: survivors are a superset of np-top-20 (tau margin); a lane would need >12
// of the global top-20 in its (chunk,residue) bucket to drop one (P ~ 1e-13, fixed data).
#define KS(A,B) V##A = (kk > V##B) ? V##B : ((kk > V##A) ? kk : V##A);
__global__ __launch_bounds__(256) void ksel(const float* __restrict__ wsf,
                                            const unsigned short* __restrict__ push,
                                            const unsigned char* __restrict__ cnt,
                                            unsigned* __restrict__ knn)
{
    #pragma clang fp contract(off)
    const float4* pts4 = (const float4*)(wsf + OFF_PTS4/4);
    const int lane = threadIdx.x & 63;
    const int q = blockIdx.x*4 + (threadIdx.x >> 6);
    float4 qp = pts4[q];

    unsigned long long V0=0,V1=0,V2=0,V3=0,V4=0,V5=0,V6=0,V7=0,V8=0,V9=0,V10=0,V11=0;

    const int c = lane >> 2, sub = lane & 3;
    int nc = (int)cnt[q*16 + c]; if (nc > 64) nc = 64;
    const unsigned short* lp = push + ((size_t)q*16 + c)*64;
    for (int i = sub; i < nc; i += 4) {
        int j = (int)lp[i];
        float4 cp = pts4[j];
        float d  = (qp.x*cp.x + qp.y*cp.y) + qp.z*cp.z;
        float pd = (2.0f*d - qp.w) - cp.w;
        unsigned long long kk = ((unsigned long long)sortable_f(pd) << 14)
                              | (unsigned long long)(16383 - j);
        if (kk > V11) {
            KS(11,10) KS(10,9) KS(9,8) KS(8,7) KS(7,6) KS(6,5)
            KS(5,4) KS(4,3) KS(3,2) KS(2,1) KS(1,0)
            V0 = (kk > V0) ? kk : V0;
        }
    }

    unsigned* kout = knn + (size_t)q*20;
    for (int it = 0; it < 20; ++it) {
        unsigned long long m = V0;
#pragma unroll
        for (int off = 32; off; off >>= 1) {
            unsigned long long o = __shfl_xor(m, off, 64);
            m = (o > m) ? o : m;
        }
        if (lane == 0) kout[it] = 16383u - (unsigned)(m & 0x3FFFull);
        bool own = (V0 == m);
        V0  = own ? V1  : V0;
        V1  = own ? V2  : V1;
        V2  = own ? V3  : V2;
        V3  = own ? V4  : V3;
        V4  = own ? V5  : V4;
        V5  = own ? V6  : V5;
        V6  = own ? V7  : V6;
        V7  = own ? V8  : V7;
        V8  = own ? V9  : V8;
        V9  = own ? V10 : V9;
        V10 = own ? V11 : V10;
        V11 = own ? 0ull : V11;
    }
}

// ---------------- kernel 5: GEMM for feature part of G and T2 ----------------
// G[n][64+o] = F_n . WA_f[o]   ;  T2[n][64+o] = F_n . WB_f[o] + CB_f[o]
__global__ __launch_bounds__(128) void kgemm(const float* __restrict__ feat,
                                             const float* __restrict__ wsf,
                                             float* __restrict__ G, float* __restrict__ T2)
{
    __shared__ float As[32][64];
    __shared__ float Bs[32][128];
    const float* WKC = wsf + OFF_WKC/4;
    const float* CBF = wsf + OFF_CBF/4;
    const int tid = threadIdx.x;
    const int n0 = blockIdx.x * 64;
    const int tx = tid & 15, ty = tid >> 4;
    float acc[8][8] = {};
    for (int kc = 0; kc < 4; ++kc) {
        int c0 = kc * 32;
        for (int i = tid; i < 2048; i += 128) {
            int cl = i >> 6, nl = i & 63;
            As[cl][nl] = feat[(size_t)(c0 + cl)*NPT + n0 + nl];
        }
        for (int i = tid; i < 4096; i += 128) {
            int cl = i >> 7, ol = i & 127;
            Bs[cl][ol] = WKC[(c0 + cl)*128 + ol];
        }
        __syncthreads();
        for (int cc = 0; cc < 32; ++cc) {
            float av[8], bv[8];
#pragma unroll
            for (int r = 0; r < 8; ++r) av[r] = As[cc][ty*8 + r];
#pragma unroll
            for (int s = 0; s < 8; ++s) bv[s] = Bs[cc][tx*8 + s];
#pragma unroll
            for (int r = 0; r < 8; ++r)
#pragma unroll
                for (int s = 0; s < 8; ++s)
                    acc[r][s] = fmaf(av[r], bv[s], acc[r][s]);
        }
        __syncthreads();
    }
#pragma unroll
    for (int r = 0; r < 8; ++r) {
        int n = n0 + ty*8 + r;
        if (tx < 8) {
            float* dst = G + (size_t)n*128 + 64 + tx*8;
#pragma unroll
            for (int s = 0; s < 8; ++s) dst[s] = acc[r][s];
        } else {
            int ob = (tx - 8)*8;
            float* dst = T2 + (size_t)n*128 + 64 + ob;
#pragma unroll
            for (int s = 0; s < 8; ++s) dst[s] = acc[r][s] + CBF[ob + s];
        }
    }
}

// ---------------- kernel 6: xyz part of G and T2 ----------------
__global__ __launch_bounds__(256) void kxpart(const float* __restrict__ xyz,
                                              const float* __restrict__ wsf,
                                              float* __restrict__ G, float* __restrict__ T2)
{
    const float4* WAX = (const float4*)(wsf + OFF_WAX/4);
    const float4* WBX = (const float4*)(wsf + OFF_WBX/4);
    const float*  CBX = wsf + OFF_CBX/4;
    const int tid = threadIdx.x;
    const int o = tid & 63;
    const int n = blockIdx.x*4 + (tid >> 6);
    float x = xyz[n], y = xyz[NPT+n], z = xyz[2*NPT+n];
    float4 A = WAX[o], B = WBX[o];
    G[(size_t)n*128 + o]  = fmaf(x, A.x, fmaf(y, A.y, z*A.z));
    T2[(size_t)n*128 + o] = fmaf(x, B.x, fmaf(y, B.y, fmaf(z, B.z, CBX[o])));
}

// ---------------- kernel 7: gather + max-pool + f1/f2 + partials ----------------
__global__ __launch_bounds__(256) void kgather(const float* __restrict__ wsf,
                                               const unsigned* __restrict__ knn,
                                               const float* __restrict__ G,
                                               const float* __restrict__ T2,
                                               const float* __restrict__ wd1,
                                               const float* __restrict__ wd2,
                                               float* __restrict__ F, float* __restrict__ F1,
                                               float* __restrict__ F2, float* __restrict__ SPm,
                                               float* __restrict__ PART)
{
    __shared__ float fsh[64][136];
    __shared__ float w1s[16][136];
    __shared__ float w2s[16][136];
    __shared__ float f1sh[64][16];
    __shared__ float f2p[64][4];
    const int tid = threadIdx.x;
    for (int i = tid; i < 2048; i += 256) {
        int o = i >> 7, cc = i & 127;
        w1s[o][cc] = wd1[i];
        w2s[o][cc] = wd2[i];
    }
    const int nl = tid >> 2, qt = tid & 3;
    const int n = blockIdx.x*64 + nl;
    const unsigned* ip = knn + (size_t)n*20;
    float acc[32];
#pragma unroll
    for (int e = 0; e < 32; ++e) acc[e] = NEG_INF;
    for (int k = 0; k < 20; ++k) {
        unsigned j = ip[k];
        const float4* g4 = (const float4*)(G + (size_t)j*128 + qt*32);
#pragma unroll
        for (int r = 0; r < 8; ++r) {
            float4 gv = g4[r];
            acc[r*4+0] = fmaxf(acc[r*4+0], gv.x);
            acc[r*4+1] = fmaxf(acc[r*4+1], gv.y);
            acc[r*4+2] = fmaxf(acc[r*4+2], gv.z);
            acc[r*4+3] = fmaxf(acc[r*4+3], gv.w);
        }
    }
    const float4* t4 = (const float4*)(T2 + (size_t)n*128 + qt*32);
    float4* fg = (float4*)(F + (size_t)n*128 + qt*32);
    float4* fs = (float4*)&fsh[nl][qt*32];
#pragma unroll
    for (int r = 0; r < 8; ++r) {
        float4 tv = t4[r];
        float4 o4;
        o4.x = fmaxf(acc[r*4+0] + tv.x, 0.f);
        o4.y = fmaxf(acc[r*4+1] + tv.y, 0.f);
        o4.z = fmaxf(acc[r*4+2] + tv.z, 0.f);
        o4.w = fmaxf(acc[r*4+3] + tv.w, 0.f);
        fg[r] = o4; fs[r] = o4;
    }
    __syncthreads();
    // phase 2: f1/f2 (4 outputs each per thread)
    float a1[4] = {0,0,0,0}, a2[4] = {0,0,0,0};
    const int ob = qt*4;
    for (int c4 = 0; c4 < 32; ++c4) {
        float4 fv = ((const float4*)&fsh[nl][0])[c4];
#pragma unroll
        for (int r = 0; r < 4; ++r) {
            float4 wv1 = ((const float4*)&w1s[ob + r][0])[c4];
            float4 wv2 = ((const float4*)&w2s[ob + r][0])[c4];
            a1[r] = fmaf(fv.x, wv1.x, fmaf(fv.y, wv1.y, fmaf(fv.z, wv1.z, fmaf(fv.w, wv1.w, a1[r]))));
            a2[r] = fmaf(fv.x, wv2.x, fmaf(fv.y, wv2.y, fmaf(fv.z, wv2.z, fmaf(fv.w, wv2.w, a2[r]))));
        }
    }
    float s2sum = 0.f;
#pragma unroll
    for (int r = 0; r < 4; ++r) {
        a1[r] = fmaxf(a1[r], 0.f);
        a2[r] = fmaxf(a2[r], 0.f);
        s2sum += a2[r];
        F1[(size_t)n*16 + ob + r] = a1[r];
        F2[(size_t)n*16 + ob + r] = a2[r];
        f1sh[nl][ob + r] = a1[r];
    }
    f2p[nl][qt] = s2sum;
    __syncthreads();
    if (qt == 0)
        SPm[n] = (f2p[nl][0] + f2p[nl][1] + f2p[nl][2] + f2p[nl][3]) * (1.0f/16.0f);
    if (tid < 16) {
        float s = 0.f;
        for (int r = 0; r < 64; ++r) s += f1sh[r][tid];
        PART[blockIdx.x*16 + tid] = s;
    }
}

// ---------------- kernel 8: reduce channel mean ----------------
__global__ __launch_bounds__(64) void kch(const float* __restrict__ PART, float* __restrict__ CH)
{
    const int tid = threadIdx.x;
    if (tid < 16) {
        float s = 0.f;
        for (int b = 0; b < 256; ++b) s += PART[b*16 + tid];
        CH[tid] = s * (1.0f/16384.0f);
    }
}

// ---------------- kernel 9: final head + mish + transpose ----------------
__global__ __launch_bounds__(64) void kfinal(const float* __restrict__ wsf,
                                             const float* __restrict__ F,
                                             const float* __restrict__ F1,
                                             const float* __restrict__ F2,
                                             const float* __restrict__ SPm,
                                             const float* __restrict__ CH,
                                             float* __restrict__ out)
{
    const float* WUP = wsf + OFF_WUP/4;
    const float* BUP = wsf + OFF_BUP/4;
    const int n = blockIdx.x*64 + threadIdx.x;
    float spv = SPm[n];
    float fin[16];
    const float4* f14 = (const float4*)(F1 + (size_t)n*16);
    const float4* f24 = (const float4*)(F2 + (size_t)n*16);
#pragma unroll
    for (int c4 = 0; c4 < 4; ++c4) {
        float4 a = f14[c4], b = f24[c4];
        fin[c4*4+0] = sqrtf(fmaf(CH[c4*4+0], spv, 1e-12f)) + a.x + b.x;
        fin[c4*4+1] = sqrtf(fmaf(CH[c4*4+1], spv, 1e-12f)) + a.y + b.y;
        fin[c4*4+2] = sqrtf(fmaf(CH[c4*4+2], spv, 1e-12f)) + a.z + b.z;
        fin[c4*4+3] = sqrtf(fmaf(CH[c4*4+3], spv, 1e-12f)) + a.w + b.w;
    }
    const float4* fF = (const float4*)(F + (size_t)n*128);
    for (int o4 = 0; o4 < 32; ++o4) {
        float4 fv = fF[o4];
        float fa[4] = {fv.x, fv.y, fv.z, fv.w};
#pragma unroll
        for (int e = 0; e < 4; ++e) {
            int o = o4*4 + e;
            float u = BUP[o];
#pragma unroll
            for (int c = 0; c < 16; ++c) u = fmaf(fin[c], WUP[o*16 + c], u);
            u = fmaxf(u, 0.f);
            float fl = fa[e] - u;
            // mish: fl * tanh(softplus(fl)) ; tanh(log1p(e^x)) = ((1+e^x)^2-1)/((1+e^x)^2+1)
            float flc = fminf(fl, 15.f);
            float t = expf(flc);
            float w = 1.f + t;
            float w2 = w*w;
            float th = (w2 - 1.f) / (w2 + 1.f);
            float res = (fl > 15.f) ? fl : fl * th;
            out[(size_t)o*NPT + n] = res;
        }
    }
}

extern "C" void kernel_launch(void* const* d_in, const int* in_sizes, int n_in,
                              void* d_out, int out_size, void* d_ws, size_t ws_size,
                              hipStream_t stream) {
    const float* xyz  = (const float*)d_in[0];
    const float* feat = (const float*)d_in[1];
    const float* w1   = (const float*)d_in[2];
    const float* b1   = (const float*)d_in[3];
    const float* g1   = (const float*)d_in[4];
    const float* bb1  = (const float*)d_in[5];
    const float* m1   = (const float*)d_in[6];
    const float* v1   = (const float*)d_in[7];
    const float* w2   = (const float*)d_in[8];
    const float* b2   = (const float*)d_in[9];
    const float* g2   = (const float*)d_in[10];
    const float* bb2  = (const float*)d_in[11];
    const float* m2   = (const float*)d_in[12];
    const float* v2   = (const float*)d_in[13];
    const float* wd1  = (const float*)d_in[14];
    const float* wd2  = (const float*)d_in[15];
    const float* wup  = (const float*)d_in[16];
    const float* bup  = (const float*)d_in[17];
    const float* gu   = (const float*)d_in[18];
    const float* bu2  = (const float*)d_in[19];
    const float* mu   = (const float*)d_in[20];
    const float* vu   = (const float*)d_in[21];
    float* out = (float*)d_out;

    float* wsf = (float*)d_ws;
    unsigned short* push = (unsigned short*)((char*)d_ws + OFF_R);
    unsigned char* cnt  = (unsigned char*)((char*)d_ws + OFF_CNT);
    unsigned* knn  = (unsigned*)((char*)d_ws + OFF_KNN);
    float* TAU  = (float*)((char*)d_ws + OFF_TAU);
    float* PART = (float*)((char*)d_ws + OFF_PART);
    float* CH   = (float*)((char*)d_ws + OFF_CH);
    // region R reused after ksel
    float* G  = (float*)((char*)d_ws + OFF_R);
    float* T2 = G  + 2097152;
    float* F  = T2 + 2097152;
    float* F1 = F  + 2097152;
    float* F2 = F1 + 262144;
    float* SPm = F2 + 262144;

    kprep<<<dim3(65),  dim3(256), 0, stream>>>(xyz, w1,b1,g1,bb1,m1,v1,
                                               w2,b2,g2,bb2,m2,v2,
                                               wup,bup,gu,bu2,mu,vu, wsf);
    ktau <<<dim3(512), dim3(256), 0, stream>>>(wsf, TAU);
    kpush<<<dim3(1024), dim3(256), 0, stream>>>(wsf, TAU, push, cnt);
    ksel <<<dim3(4096), dim3(256), 0, stream>>>(wsf, push, cnt, knn);
    kgemm<<<dim3(256), dim3(128), 0, stream>>>(feat, wsf, G, T2);
    kxpart<<<dim3(4096), dim3(256), 0, stream>>>(xyz, wsf, G, T2);
    kgather<<<dim3(256), dim3(256), 0, stream>>>(wsf, knn, G, T2, wd1, wd2, F, F1, F2, SPm, PART);
    kch  <<<dim3(1),   dim3(64), 0, stream>>>(PART, CH);
    kfinal<<<dim3(256), dim3(64), 0, stream>>>(wsf, F, F1, F2, SPm, CH, out);
}